// Round 10
// baseline (222.866 us; speedup 1.0000x reference)
//
#include <hip/hip_runtime.h>
#include <hip/hip_bf16.h>

// Cholesky-QR Gram-Schmidt, 16 vectors x dim-256, 32768 rows, fp32,
// layout (16, 32768, 256).
//
// R10: 2 rows per wave, software-pipelined. Both rows' 32 global loads
// issue up-front; row A's full compute (stage -> MFMA -> chol -> stores)
// covers row B's load latency; B reuses the same LDS buffer. One wave per
// block -> no __syncthreads (which would s_waitcnt vmcnt(0) and drain B's
// in-flight loads); per-wave LDS ordering enforced with lgkmcnt(0) +
// sched_barrier(0) at phase boundaries (LDS pipe is in-order per wave,
// compiler adds its own waits for same-object deps).

constexpr int NM   = 16;     // vectors per row
constexpr int NR   = 32768;  // rows
constexpr int D4   = 64;     // float4 per vector
constexpr int LROW = 264;    // bf16 row stride in LDS (padded)

typedef __attribute__((ext_vector_type(8))) short short8v;  // 8 x bf16
typedef __attribute__((ext_vector_type(4))) float f32x4;

__device__ __forceinline__ float rl(float x, int lane) {
    return __builtin_bit_cast(float,
        __builtin_amdgcn_readlane(__builtin_bit_cast(int, x), lane));
}

__global__ __launch_bounds__(64) void gs_kernel(const float* __restrict__ x,
                                                float* __restrict__ out) {
    __shared__ __align__(16) unsigned short sm_hi[NM * LROW];  // 8448 B
    __shared__ __align__(16) unsigned short sm_lo[NM * LROW];  // 8448 B

    const int lane = threadIdx.x;
    const int vec  = lane & 15;   // vector owned in the MFMA fragment
    const int kgrp = lane >> 4;   // k-group 0..3
    const int rowA = blockIdx.x * 2;
    const int rowB = rowA + 1;

    const float4* __restrict__ xi = reinterpret_cast<const float4*>(x);
    float4* __restrict__ oo       = reinterpret_cast<float4*>(out);

    // Issue BOTH rows' loads up-front (32 x dwordx4 in flight).
    float4 vA[NM], vB[NM];
#pragma unroll
    for (int i = 0; i < NM; ++i)
        vA[i] = xi[(size_t)(i * NR + rowA) * D4 + lane];
#pragma unroll
    for (int i = 0; i < NM; ++i)
        vB[i] = xi[(size_t)(i * NR + rowB) * D4 + lane];

    // Stage one row's bf16 hi/lo split into LDS (lane l -> elems 4l..4l+3).
    auto stage = [&](const float4* v) {
#pragma unroll
        for (int i = 0; i < NM; ++i) {
            float f[4] = {v[i].x, v[i].y, v[i].z, v[i].w};
            ushort4 hp, lp;
            unsigned short* hh = &hp.x;
            unsigned short* ll = &lp.x;
#pragma unroll
            for (int j = 0; j < 4; ++j) {
                unsigned short hb =
                    __builtin_bit_cast(unsigned short, __float2bfloat16(f[j]));
                hh[j] = hb;
                float hv = __builtin_bit_cast(float, (unsigned int)hb << 16);
                ll[j] = __builtin_bit_cast(unsigned short,
                                           __float2bfloat16(f[j] - hv));
            }
            *reinterpret_cast<ushort4*>(&sm_hi[i * LROW + 4 * lane]) = hp;
            *reinterpret_cast<ushort4*>(&sm_lo[i * LROW + 4 * lane]) = lp;
        }
    };

    // G = V V^T via MFMA (hi/lo split, 3 terms), frags from LDS.
    auto gram = [&]() {
        f32x4 g = {0.0f, 0.0f, 0.0f, 0.0f};
#pragma unroll
        for (int c = 0; c < 8; ++c) {
            const int off = vec * LROW + c * 32 + kgrp * 8;
            short8v ah = *reinterpret_cast<const short8v*>(&sm_hi[off]);
            short8v al = *reinterpret_cast<const short8v*>(&sm_lo[off]);
            g = __builtin_amdgcn_mfma_f32_16x16x32_bf16(ah, ah, g, 0, 0, 0);
            g = __builtin_amdgcn_mfma_f32_16x16x32_bf16(ah, al, g, 0, 0, 0);
            g = __builtin_amdgcn_mfma_f32_16x16x32_bf16(al, ah, g, 0, 0, 0);
        }
        return g;
    };

    // shfl G-row + fused Cholesky / forward substitution + stores.
    auto solve = [&](f32x4 g, float4* v, int row) {
        float a[NM];
#pragma unroll
        for (int n = 0; n < NM; ++n)
            a[n] = __shfl(g[n & 3], vec + 16 * (n >> 2), 64);
#pragma unroll
        for (int j = 0; j < NM; ++j) {
            float p   = rl(a[j], j);
            float inv = (p > 0.0f) ? rsqrtf(p) : 0.0f;   // safe-div
            v[j].x *= inv; v[j].y *= inv; v[j].z *= inv; v[j].w *= inv;
            oo[(size_t)(j * NR + row) * D4 + lane] = v[j];
            a[j] *= inv;
#pragma unroll
            for (int t = j + 1; t < NM; ++t) {
                float u = rl(a[j], t);
                a[t]  = fmaf(-u, a[j], a[t]);
                v[t].x = fmaf(-u, v[j].x, v[t].x);
                v[t].y = fmaf(-u, v[j].y, v[t].y);
                v[t].z = fmaf(-u, v[j].z, v[t].z);
                v[t].w = fmaf(-u, v[j].w, v[t].w);
            }
        }
    };

    // ---- row A ----
    stage(vA);                                   // waits on vA loads only
    asm volatile("s_waitcnt lgkmcnt(0)" ::: "memory");
    __builtin_amdgcn_sched_barrier(0);
    f32x4 gA = gram();                           // A frag reads + MFMA
    __builtin_amdgcn_sched_barrier(0);           // B writes stay after A reads

    // ---- row B staging (loads landed during A's compute) ----
    stage(vB);
    asm volatile("s_waitcnt lgkmcnt(0)" ::: "memory");
    __builtin_amdgcn_sched_barrier(0);

    // B's MFMA adjacent to A's solve: scheduler may interleave MFMA/ds_read
    // latency with solve-A VALU.
    f32x4 gB = gram();
    solve(gA, vA, rowA);
    solve(gB, vB, rowB);
}

extern "C" void kernel_launch(void* const* d_in, const int* in_sizes, int n_in,
                              void* d_out, int out_size, void* d_ws, size_t ws_size,
                              hipStream_t stream) {
    const float* x = (const float*)d_in[0];
    float* out     = (float*)d_out;
    dim3 grid(NR / 2);   // one wave per block, 2 rows per wave
    dim3 block(64);
    hipLaunchKernelGGL(gs_kernel, grid, block, 0, stream, x, out);
}